// Round 4
// baseline (164.939 us; speedup 1.0000x reference)
//
#include <hip/hip_runtime.h>

// ---------------------------------------------------------------------------
// MHSA fused block, MI355X (gfx950).
// fold(BN->W) -> pos table -> QKV projection GEMM (bf16 MFMA, hi/lo split
// for q,k) -> flash attention (double-buffered gload_lds pipeline, per-wave
// LDS P-transpose (round-2-proven), XCD-local L2 reuse).
// ---------------------------------------------------------------------------

typedef __attribute__((ext_vector_type(8))) short bf16x8;
typedef __attribute__((ext_vector_type(4))) float f32x4;
typedef __attribute__((ext_vector_type(4))) unsigned int u32x4;

#define MFMA16(a, b, c) __builtin_amdgcn_mfma_f32_16x16x32_bf16(a, b, c, 0, 0, 0)

__device__ __forceinline__ unsigned short f2bf(float f) {
  union { float f; unsigned u; } v; v.f = f;
  unsigned r = v.u + 0x7fffu + ((v.u >> 16) & 1u);
  return (unsigned short)(r >> 16);
}
__device__ __forceinline__ float bf2f(unsigned short h) {
  union { unsigned u; float f; } v; v.u = ((unsigned)h) << 16;
  return v.f;
}

// 16B global -> LDS direct (wave-uniform LDS base + lane*16)
__device__ __forceinline__ void gload16(const void* g, void* l) {
  __builtin_amdgcn_global_load_lds(
      (const __attribute__((address_space(1))) void*)g,
      (__attribute__((address_space(3))) void*)l, 16, 0, 0);
}

// ---------------------------------------------------------------------------
__global__ __launch_bounds__(256) void fold_kernel(
    const float* __restrict__ Wq, const float* __restrict__ bq,
    const float* __restrict__ qg, const float* __restrict__ qbe,
    const float* __restrict__ qme, const float* __restrict__ qva,
    const float* __restrict__ Wk, const float* __restrict__ bk,
    const float* __restrict__ kg, const float* __restrict__ kbe,
    const float* __restrict__ kme, const float* __restrict__ kva,
    const float* __restrict__ Wv, const float* __restrict__ bv,
    const float* __restrict__ vg, const float* __restrict__ vbe,
    const float* __restrict__ vme, const float* __restrict__ vva,
    unsigned short* __restrict__ Wf, unsigned short* __restrict__ Wflo,
    float* __restrict__ bfv)
{
  int idx = blockIdx.x * 256 + threadIdx.x;
  if (idx >= 768 * 512) return;
  int o = idx >> 9, c = idx & 511;
  float w, sc, bb, mean, beta;
  if (o < 128) {
    sc = qg[o] / sqrtf(qva[o] + 1e-5f);
    w = Wq[o * 512 + c]; bb = bq[o]; mean = qme[o]; beta = qbe[o];
  } else if (o < 256) {
    int r = o - 128;
    sc = kg[r] / sqrtf(kva[r] + 1e-5f);
    w = Wk[r * 512 + c]; bb = bk[r]; mean = kme[r]; beta = kbe[r];
  } else {
    int r = o - 256;
    sc = vg[r] / sqrtf(vva[r] + 1e-5f);
    w = Wv[r * 512 + c]; bb = bv[r]; mean = vme[r]; beta = vbe[r];
  }
  float wsc = w * sc;
  unsigned uw = __float_as_uint(wsc);
  unsigned short hi = (unsigned short)(uw >> 16);
  Wf[idx] = hi;
  if (o < 256) {
    float lof = wsc - __uint_as_float(uw & 0xffff0000u);
    Wflo[idx] = (unsigned short)(__float_as_uint(lof) >> 16);
  }
  if (c == 0) bfv[o] = (bb - mean) * sc + beta;
}

// ---------------------------------------------------------------------------
__global__ __launch_bounds__(256) void pos_kernel(
    const float* __restrict__ rel_h, const float* __restrict__ rel_w,
    unsigned short* __restrict__ posT, unsigned short* __restrict__ posTlo)
{
  int idx = blockIdx.x * 256 + threadIdx.x;  // [h][n][d] : 4*1024*32
  if (idx >= 4 * 1024 * 32) return;
  int h = idx >> 15, rem = idx & 32767, n = rem >> 5, d = rem & 31;
  int w = n >> 5, hh = n & 31;
  float v = rel_h[(h * 32 + d) * 32 + hh] + rel_w[(h * 32 + d) * 32 + w];
  unsigned uv = __float_as_uint(v);
  posT[idx] = (unsigned short)(uv >> 16);
  float lof = v - __uint_as_float(uv & 0xffff0000u);
  posTlo[idx] = (unsigned short)(__float_as_uint(lof) >> 16);
}

// ---------------------------------------------------------------------------
// Projection GEMM (unchanged from round 2 — validated).
// ---------------------------------------------------------------------------
__global__ __launch_bounds__(256) void proj_kernel(
    const float* __restrict__ x,
    const unsigned short* __restrict__ Wf, const unsigned short* __restrict__ Wflo,
    const float* __restrict__ bfv,
    unsigned short* __restrict__ qT, unsigned short* __restrict__ qloT,
    unsigned short* __restrict__ kT, unsigned short* __restrict__ kloT,
    unsigned short* __restrict__ Vm)
{
  __shared__ __align__(16) short sm[24576];
  short* At  = sm;
  short* Bt  = sm + 8192;
  short* Btl = sm + 16384;

  int bid = blockIdx.x;
  int b = bid / 48, rem = bid % 48, mblk = rem >> 3, nblk = rem & 7;
  int Mb = mblk * 128, Nb = nblk * 128;
  bool prec = (mblk < 2);
  int t = threadIdx.x;
  int lane = t & 63, wvid = t >> 6, ln = lane & 15, g = lane >> 4;
  int wm = wvid >> 1, wn = wvid & 1;
  int kgp = t >> 5, lp = t & 31;

  f32x4 acc[4][4];
  for (int i = 0; i < 4; i++)
    for (int j = 0; j < 4; j++) acc[i][j] = (f32x4){0.f, 0.f, 0.f, 0.f};

  for (int kb = 0; kb < 512; kb += 64) {
    __syncthreads();
    for (int ii = 0; ii < 4; ii++) {
      int idx = ii * 256 + t;
      int row = idx >> 3, pos = idx & 7;
      int j = pos ^ (row & 7);
      *(bf16x8*)&At[row * 64 + pos * 8] =
          *(const bf16x8*)&Wf[(Mb + row) * 512 + kb + j * 8];
    }
    for (int e = 0; e < 2; e++) {
      float2 f[8];
      for (int rr = 0; rr < 8; rr++)
        f[rr] = *(const float2*)&x[(b * 512 + kb + kgp * 8 + rr) * 1024 +
                                   Nb + 2 * lp + 64 * e];
      int n0 = 2 * lp + 64 * e, n1 = n0 + 1;
      unsigned h0[4], h1[4], l0[4], l1[4];
      for (int pr = 0; pr < 4; pr++) {
        unsigned ua = __float_as_uint(f[2 * pr].x);
        unsigned ub = __float_as_uint(f[2 * pr + 1].x);
        unsigned va = __float_as_uint(f[2 * pr].y);
        unsigned vb = __float_as_uint(f[2 * pr + 1].y);
        h0[pr] = (ua >> 16) | (ub & 0xffff0000u);
        h1[pr] = (va >> 16) | (vb & 0xffff0000u);
        if (prec) {
          float lax = f[2 * pr].x - __uint_as_float(ua & 0xffff0000u);
          float lbx = f[2 * pr + 1].x - __uint_as_float(ub & 0xffff0000u);
          float lay = f[2 * pr].y - __uint_as_float(va & 0xffff0000u);
          float lby = f[2 * pr + 1].y - __uint_as_float(vb & 0xffff0000u);
          l0[pr] = (__float_as_uint(lax) >> 16) | (__float_as_uint(lbx) & 0xffff0000u);
          l1[pr] = (__float_as_uint(lay) >> 16) | (__float_as_uint(lby) & 0xffff0000u);
        }
      }
      *(u32x4*)&Bt[n0 * 64 + 8 * (kgp ^ (n0 & 7))] = (u32x4){h0[0], h0[1], h0[2], h0[3]};
      *(u32x4*)&Bt[n1 * 64 + 8 * (kgp ^ (n1 & 7))] = (u32x4){h1[0], h1[1], h1[2], h1[3]};
      if (prec) {
        *(u32x4*)&Btl[n0 * 64 + 8 * (kgp ^ (n0 & 7))] = (u32x4){l0[0], l0[1], l0[2], l0[3]};
        *(u32x4*)&Btl[n1 * 64 + 8 * (kgp ^ (n1 & 7))] = (u32x4){l1[0], l1[1], l1[2], l1[3]};
      }
    }
    __syncthreads();

    bf16x8 afh[4][2], afl[4][2], bfh[4][2], bfl[4][2];
    for (int mt = 0; mt < 4; mt++)
      for (int ks = 0; ks < 2; ks++) {
        int o = wm * 64 + mt * 16 + ln;
        afh[mt][ks] = *(const bf16x8*)&At[o * 64 + 8 * ((ks * 4 + g) ^ (o & 7))];
        if (prec)
          afl[mt][ks] = *(const bf16x8*)&Wflo[(Mb + o) * 512 + kb + ks * 32 + g * 8];
      }
    for (int nt = 0; nt < 4; nt++)
      for (int ks = 0; ks < 2; ks++) {
        int n = wn * 64 + nt * 16 + ln;
        int so = n * 64 + 8 * ((ks * 4 + g) ^ (n & 7));
        bfh[nt][ks] = *(const bf16x8*)&Bt[so];
        if (prec) bfl[nt][ks] = *(const bf16x8*)&Btl[so];
      }
    for (int ks = 0; ks < 2; ks++)
      for (int mt = 0; mt < 4; mt++)
        for (int nt = 0; nt < 4; nt++) {
          acc[mt][nt] = MFMA16(afh[mt][ks], bfh[nt][ks], acc[mt][nt]);
          if (prec) {
            acc[mt][nt] = MFMA16(afh[mt][ks], bfl[nt][ks], acc[mt][nt]);
            acc[mt][nt] = MFMA16(afl[mt][ks], bfh[nt][ks], acc[mt][nt]);
          }
        }
  }

  unsigned* smU = (unsigned*)sm;
  for (int p = 0; p < 2; p++) {
    __syncthreads();
    if (wn == p) {
      if (mblk < 2) {
        for (int mt = 0; mt < 4; mt++)
          for (int nt = 0; nt < 4; nt++) {
            u32x4 pk;
            for (int r = 0; r < 4; r++) {
              int o = wm * 64 + mt * 16 + g * 4 + r;
              float y = acc[mt][nt][r] + bfv[Mb + o];
              unsigned uy = __float_as_uint(y);
              float lof = y - __uint_as_float(uy & 0xffff0000u);
              pk[r] = (uy >> 16) | (__float_as_uint(lof) & 0xffff0000u);
            }
            int nl = nt * 16 + ln;
            *(u32x4*)&smU[nl * 132 + wm * 64 + mt * 16 + g * 4] = pk;
          }
      } else {
        for (int mt = 0; mt < 4; mt++)
          for (int nt = 0; nt < 4; nt++)
            for (int r = 0; r < 4; r++) {
              int o = wm * 64 + mt * 16 + g * 4 + r;
              float y = acc[mt][nt][r] + bfv[Mb + o];
              sm[o * 72 + nt * 16 + ln] = (short)f2bf(y);
            }
      }
    }
    __syncthreads();
    if (mblk < 2) {
      unsigned short* dh = (mblk == 0) ? qT : kT;
      unsigned short* dl = (mblk == 0) ? qloT : kloT;
      for (int it = 0; it < 4; it++) {
        int task = it * 256 + t;
        int h = task >> 8, nl = (task >> 2) & 63, qc = task & 3;
        const unsigned* src = &smU[nl * 132 + h * 32 + qc * 8];
        u32x4 ua = *(const u32x4*)src;
        u32x4 ub = *(const u32x4*)(src + 4);
        u32x4 hi, lo;
        hi[0] = (ua[0] & 0xffffu) | (ua[1] << 16);
        hi[1] = (ua[2] & 0xffffu) | (ua[3] << 16);
        hi[2] = (ub[0] & 0xffffu) | (ub[1] << 16);
        hi[3] = (ub[2] & 0xffffu) | (ub[3] << 16);
        lo[0] = (ua[0] >> 16) | (ua[1] & 0xffff0000u);
        lo[1] = (ua[2] >> 16) | (ua[3] & 0xffff0000u);
        lo[2] = (ub[0] >> 16) | (ub[1] & 0xffff0000u);
        lo[3] = (ub[2] >> 16) | (ub[3] & 0xffff0000u);
        int gi = ((b * 4 + h) * 1024 + Nb + p * 64 + nl) * 32 + qc * 8;
        *(u32x4*)&dh[gi] = hi;
        *(u32x4*)&dl[gi] = lo;
      }
    } else {
      int bh = b * 4 + (mblk - 2);
      for (int it = 0; it < 4; it++) {
        int task = it * 256 + t;
        int o = task >> 3, qc = task & 7;
        u32x4 vv = *(const u32x4*)&sm[o * 72 + qc * 8];
        *(u32x4*)&Vm[(bh * 128 + o) * 1024 + Nb + p * 64 + qc * 8] = vv;
      }
    }
  }
}

// ---------------------------------------------------------------------------
// Flash attention, double-buffered pipeline.
// LDS per buffer (shorts): Khi[64][32]@0, Klo@2048, Qhi@4096, Qlo@6144
// (chunk-swizzled: pos = ch ^ (r&3) ^ ((r>>2)&3)), V[128][8 chunks]@8192
// (pos = ch ^ (c&7)). Buffer = 16384 shorts; 2 buffers = 64 KB.
// P-transpose: per-wave LDS buffer [16][72] @32768 (round-2-proven formulas),
// processed qs-sequentially.
// Schedule: STAGE(next); vmcnt(8); barrier; compute(cur); barrier.
// ---------------------------------------------------------------------------
__global__ __launch_bounds__(256) void attn_kernel(
    const float* __restrict__ x,
    const unsigned short* __restrict__ qT, const unsigned short* __restrict__ qloT,
    const unsigned short* __restrict__ kT, const unsigned short* __restrict__ kloT,
    const unsigned short* __restrict__ posT, const unsigned short* __restrict__ posTlo,
    const unsigned short* __restrict__ Vm,
    float* __restrict__ out)
{
  __shared__ __align__(16) short sm[2 * 16384 + 4 * 16 * 72];  // 73 KB

  int bid = blockIdx.x;
  // XCD-local mapping: all 8 q-tiles of a head on one XCD
  int bh = (bid & 7) * 8 + ((bid >> 3) & 7);
  int qt = bid >> 6;
  int b = bh >> 2, h = bh & 3;
  int t = threadIdx.x;
  int lane = t & 63, wvid = t >> 6, ln = lane & 15, g = lane >> 4;

  // own-query B-fragments
  bf16x8 bQh[2], bQl[2], bPh[2], bPl[2];
  for (int qs = 0; qs < 2; qs++) {
    int qrow = qt * 128 + wvid * 32 + qs * 16 + ln;
    int gi = (bh * 1024 + qrow) * 32 + g * 8;
    bQh[qs] = *(const bf16x8*)&qT[gi];
    bQl[qs] = *(const bf16x8*)&qloT[gi];
    int pi = (h * 1024 + qrow) * 32 + g * 8;
    bPh[qs] = *(const bf16x8*)&posT[pi];
    bPl[qs] = *(const bf16x8*)&posTlo[pi];
  }

  f32x4 acc[2][8];
  for (int qs = 0; qs < 2; qs++)
    for (int ct = 0; ct < 8; ct++) acc[qs][ct] = (f32x4){0.f, 0.f, 0.f, 0.f};
  float m_run[2] = {-1e30f, -1e30f};
  float l_run[2] = {0.f, 0.f};

  short* Pw = &sm[32768 + wvid * 1152];

  // ---- staging: 8 gload_lds per thread into buffer bb
  auto STAGE = [&](int bb, int jb) {
    int q = wvid * 64 + lane;
    int r = q >> 2;
    int ch = (q & 3) ^ (r & 3) ^ ((r >> 2) & 3);
    long gq = (long)(bh * 1024 + jb + r) * 32 + ch * 8;
    short* base = &sm[bb * 16384 + wvid * 512];
    gload16(&kT[gq],   base);
    gload16(&kloT[gq], base + 2048);
    gload16(&qT[gq],   base + 4096);
    gload16(&qloT[gq], base + 6144);
    for (int i = 0; i < 4; i++) {
      int qv = (wvid * 4 + i) * 64 + lane;
      int c = qv >> 3;
      int vch = (qv & 7) ^ (c & 7);
      long gv = (long)(bh * 128 + c) * 1024 + jb + vch * 8;
      gload16(&Vm[gv], &sm[bb * 16384 + 8192 + (wvid * 4 + i) * 512]);
    }
  };

  STAGE(0, 0);

  for (int it = 0; it < 16; ++it) {
    int cur = it & 1;
    if (it < 15) {
      STAGE(cur ^ 1, (it + 1) * 64);
      asm volatile("s_waitcnt vmcnt(8)" ::: "memory");
    } else {
      asm volatile("s_waitcnt vmcnt(0)" ::: "memory");
    }
    __builtin_amdgcn_sched_barrier(0);
    __builtin_amdgcn_s_barrier();
    __builtin_amdgcn_sched_barrier(0);

    const short* B = &sm[cur * 16384];

    bf16x8 aKh[4], aKl[4], aQh[4], aQl[4];
    for (int kt = 0; kt < 4; kt++) {
      int r = kt * 16 + ln;
      int p = g ^ (r & 3) ^ ((r >> 2) & 3);
      int off = r * 32 + p * 8;
      aKh[kt] = *(const bf16x8*)&B[off];
      aKl[kt] = *(const bf16x8*)&B[2048 + off];
      aQh[kt] = *(const bf16x8*)&B[4096 + off];
      aQl[kt] = *(const bf16x8*)&B[6144 + off];
    }

    bf16x8 bP[2][2];
    for (int qs = 0; qs < 2; qs++) {
      f32x4 s[4];
      for (int kt = 0; kt < 4; kt++) s[kt] = (f32x4){0.f, 0.f, 0.f, 0.f};
      for (int kt = 0; kt < 4; kt++) s[kt] = MFMA16(aKh[kt], bQh[qs], s[kt]);
      for (int kt = 0; kt < 4; kt++) s[kt] = MFMA16(aKh[kt], bQl[qs], s[kt]);
      for (int kt = 0; kt < 4; kt++) s[kt] = MFMA16(aKl[kt], bQh[qs], s[kt]);
      for (int kt = 0; kt < 4; kt++) s[kt] = MFMA16(aQh[kt], bPh[qs], s[kt]);
      for (int kt = 0; kt < 4; kt++) s[kt] = MFMA16(aQh[kt], bPl[qs], s[kt]);
      for (int kt = 0; kt < 4; kt++) s[kt] = MFMA16(aQl[kt], bPh[qs], s[kt]);

      // online softmax (query i = ln), defer-rescale when max doesn't grow
      float mx = -1e30f;
      for (int kt = 0; kt < 4; kt++)
        for (int r = 0; r < 4; r++) mx = fmaxf(mx, s[kt][r]);
      mx = fmaxf(mx, __shfl_xor(mx, 16));
      mx = fmaxf(mx, __shfl_xor(mx, 32));
      float mnew;
      if (__any(mx > m_run[qs])) {
        mnew = fmaxf(m_run[qs], mx);
        float scl = __expf(m_run[qs] - mnew);
        l_run[qs] *= scl;
        for (int ct = 0; ct < 8; ct++) acc[qs][ct] *= scl;
      } else {
        mnew = m_run[qs];
      }
      float rs = 0.f;
      for (int kt = 0; kt < 4; kt++)
        for (int r = 0; r < 4; r++) {
          float pv = __expf(s[kt][r] - mnew);
          s[kt][r] = pv;
          rs += pv;
        }
      rs += __shfl_xor(rs, 16);
      rs += __shfl_xor(rs, 32);
      l_run[qs] += rs;
      m_run[qs] = mnew;

      // P^T -> per-wave LDS [i=ln][j] (round-2-proven formulas)
      for (int kt = 0; kt < 4; kt++)
        for (int pr = 0; pr < 2; pr++) {
          unsigned pk = (unsigned)f2bf(s[kt][2 * pr]) |
                        ((unsigned)f2bf(s[kt][2 * pr + 1]) << 16);
          *(unsigned*)&Pw[ln * 72 + kt * 16 + g * 4 + pr * 2] = pk;
        }
      asm volatile("s_waitcnt lgkmcnt(0)" ::: "memory");
      __builtin_amdgcn_sched_barrier(0);
      for (int st2 = 0; st2 < 2; st2++)
        bP[qs][st2] = *(const bf16x8*)&Pw[ln * 72 + st2 * 32 + g * 8];
      asm volatile("s_waitcnt lgkmcnt(0)" ::: "memory");
      __builtin_amdgcn_sched_barrier(0);
    }

    // PV: acc[qs][ct] += V[c][j] * P[i][j]
    for (int ct = 0; ct < 8; ct++)
      for (int st2 = 0; st2 < 2; st2++) {
        int c = ct * 16 + ln;
        int pos = (st2 * 4 + g) ^ (c & 7);
        bf16x8 av = *(const bf16x8*)&B[8192 + c * 64 + pos * 8];
        acc[0][ct] = MFMA16(av, bP[0][st2], acc[0][ct]);
        acc[1][ct] = MFMA16(av, bP[1][st2], acc[1][ct]);
      }

    __builtin_amdgcn_sched_barrier(0);
    __builtin_amdgcn_s_barrier();
    __builtin_amdgcn_sched_barrier(0);
  }

  // epilogue: normalize, residual, store
  for (int qs = 0; qs < 2; qs++) {
    float inv = 1.0f / l_run[qs];
    int m = qt * 128 + wvid * 32 + qs * 16 + ln;
    for (int ct = 0; ct < 8; ct++)
      for (int r = 0; r < 4; r++) {
        int c = h * 128 + ct * 16 + g * 4 + r;
        int gi = (b * 512 + c) * 1024 + m;
        out[gi] = acc[qs][ct][r] * inv + x[gi];
      }
  }
}

// ---------------------------------------------------------------------------
extern "C" void kernel_launch(void* const* d_in, const int* in_sizes, int n_in,
                              void* d_out, int out_size, void* d_ws, size_t ws_size,
                              hipStream_t stream) {
  const float* x    = (const float*)d_in[0];
  const float* Wq   = (const float*)d_in[1];
  const float* bq   = (const float*)d_in[2];
  const float* qg   = (const float*)d_in[3];
  const float* qbe  = (const float*)d_in[4];
  const float* qme  = (const float*)d_in[5];
  const float* qva  = (const float*)d_in[6];
  const float* Wk   = (const float*)d_in[7];
  const float* bk   = (const float*)d_in[8];
  const float* kg   = (const float*)d_in[9];
  const float* kbe  = (const float*)d_in[10];
  const float* kme  = (const float*)d_in[11];
  const float* kva  = (const float*)d_in[12];
  const float* Wv   = (const float*)d_in[13];
  const float* bv   = (const float*)d_in[14];
  const float* vg   = (const float*)d_in[15];
  const float* vbe  = (const float*)d_in[16];
  const float* vme  = (const float*)d_in[17];
  const float* vva  = (const float*)d_in[18];
  const float* relh = (const float*)d_in[19];
  const float* relw = (const float*)d_in[20];
  float* outp = (float*)d_out;

  unsigned char* ws = (unsigned char*)d_ws;
  unsigned short* Wf     = (unsigned short*)(ws + 0);
  unsigned short* Wflo   = (unsigned short*)(ws + 786432);
  float*          bfv    = (float*)(ws + 1048576);
  unsigned short* qTp    = (unsigned short*)(ws + 1051648);
  unsigned short* qloTp  = (unsigned short*)(ws + 5245952);
  unsigned short* kTp    = (unsigned short*)(ws + 9440256);
  unsigned short* kloTp  = (unsigned short*)(ws + 13634560);
  unsigned short* posTp  = (unsigned short*)(ws + 17828864);
  unsigned short* posTlp = (unsigned short*)(ws + 18091008);
  unsigned short* Vmp    = (unsigned short*)(ws + 18353152);

  fold_kernel<<<1536, 256, 0, stream>>>(Wq, bq, qg, qbe, qme, qva,
                                        Wk, bk, kg, kbe, kme, kva,
                                        Wv, bv, vg, vbe, vme, vva,
                                        Wf, Wflo, bfv);
  pos_kernel<<<512, 256, 0, stream>>>(relh, relw, posTp, posTlp);
  proj_kernel<<<768, 256, 0, stream>>>(x, Wf, Wflo, bfv,
                                       qTp, qloTp, kTp, kloTp, Vmp);
  attn_kernel<<<512, 256, 0, stream>>>(x, qTp, qloTp, kTp, kloTp,
                                       posTp, posTlp, Vmp, outp);
}

// Round 6
// 96.834 us; speedup vs baseline: 1.7033x; 1.7033x over previous
//
#include <hip/hip_runtime.h>

// ---------------------------------------------------------------------------
// MHSA fused block, MI355X (gfx950).
// fold(BN->W, fp16, q-rows pre-scaled by log2e) -> pos table (fp16) ->
// QKV projection GEMM (fp16 MFMA single-pass) -> flash attention
// (fp16 scores/P/V, exp2-domain softmax, dbuf gload_lds pipeline,
// per-wave LDS P-transpose, XCD-local L2 reuse).
// ---------------------------------------------------------------------------

typedef _Float16 f16x8 __attribute__((ext_vector_type(8)));
typedef __attribute__((ext_vector_type(4))) float f32x4;
typedef __attribute__((ext_vector_type(4))) unsigned int u32x4;
typedef __attribute__((ext_vector_type(2))) unsigned int u32x2;

#define MFMAH(a, b, c) __builtin_amdgcn_mfma_f32_16x16x32_f16(a, b, c, 0, 0, 0)
#define LOG2E 1.4426950408889634f

__device__ __forceinline__ unsigned pkh(float a, float b) {
  auto p = __builtin_amdgcn_cvt_pkrtz(a, b);  // __fp16 ext_vector(2)
  return __builtin_bit_cast(unsigned, p);
}
__device__ __forceinline__ short f2h(float a) {
  _Float16 h = (_Float16)a;
  return __builtin_bit_cast(short, h);
}

// 16B global -> LDS direct (wave-uniform LDS base + lane*16)
__device__ __forceinline__ void gload16(const void* g, void* l) {
  __builtin_amdgcn_global_load_lds(
      (const __attribute__((address_space(1))) void*)g,
      (__attribute__((address_space(3))) void*)l, 16, 0, 0);
}

// ---------------------------------------------------------------------------
// Fold BN into conv weights -> fp16. Wh[768][512] (rows: 128 q, 128 k, 512 v).
// q rows (and q bias) pre-scaled by log2e so softmax runs in exp2 domain.
// ---------------------------------------------------------------------------
__global__ __launch_bounds__(256) void fold_kernel(
    const float* __restrict__ Wq, const float* __restrict__ bq,
    const float* __restrict__ qg, const float* __restrict__ qbe,
    const float* __restrict__ qme, const float* __restrict__ qva,
    const float* __restrict__ Wk, const float* __restrict__ bk,
    const float* __restrict__ kg, const float* __restrict__ kbe,
    const float* __restrict__ kme, const float* __restrict__ kva,
    const float* __restrict__ Wv, const float* __restrict__ bv,
    const float* __restrict__ vg, const float* __restrict__ vbe,
    const float* __restrict__ vme, const float* __restrict__ vva,
    unsigned short* __restrict__ Wh, float* __restrict__ bfv)
{
  int idx = blockIdx.x * 256 + threadIdx.x;
  if (idx >= 768 * 512) return;
  int o = idx >> 9, c = idx & 511;
  float w, sc, bb, mean, beta, post;
  if (o < 128) {
    sc = qg[o] / sqrtf(qva[o] + 1e-5f);
    w = Wq[o * 512 + c]; bb = bq[o]; mean = qme[o]; beta = qbe[o];
    post = LOG2E;
  } else if (o < 256) {
    int r = o - 128;
    sc = kg[r] / sqrtf(kva[r] + 1e-5f);
    w = Wk[r * 512 + c]; bb = bk[r]; mean = kme[r]; beta = kbe[r];
    post = 1.0f;
  } else {
    int r = o - 256;
    sc = vg[r] / sqrtf(vva[r] + 1e-5f);
    w = Wv[r * 512 + c]; bb = bv[r]; mean = vme[r]; beta = vbe[r];
    post = 1.0f;
  }
  Wh[idx] = (unsigned short)f2h(w * sc * post);
  if (c == 0) bfv[o] = ((bb - mean) * sc + beta) * post;
}

// ---------------------------------------------------------------------------
// pos[h][n][d] = rel_h[h,d,hh] + rel_w[h,d,w], n = w*32+hh -> fp16.
// (NOT log2e-scaled: the q factor in the cp term carries the scale.)
// ---------------------------------------------------------------------------
__global__ __launch_bounds__(256) void pos_kernel(
    const float* __restrict__ rel_h, const float* __restrict__ rel_w,
    unsigned short* __restrict__ posH)
{
  int idx = blockIdx.x * 256 + threadIdx.x;  // [h][n][d] : 4*1024*32
  if (idx >= 4 * 1024 * 32) return;
  int h = idx >> 15, rem = idx & 32767, n = rem >> 5, d = rem & 31;
  int w = n >> 5, hh = n & 31;
  float v = rel_h[(h * 32 + d) * 32 + hh] + rel_w[(h * 32 + d) * 32 + w];
  posH[idx] = (unsigned short)f2h(v);
}

// ---------------------------------------------------------------------------
// Projection GEMM: per batch b, Y[768][1024] = Wh[768][512] * x_b[512][1024].
// fp16 single-pass MFMA, tile 128x128, BK=64, 4 waves. LDS 32KB -> 3 blk/CU.
// Epilogue via LDS transpose -> coalesced 16B stores.
//   qH/kH [B*H][1024][32] fp16 (position-major), vH [B*H][128][1024] fp16.
// ---------------------------------------------------------------------------
__global__ __launch_bounds__(256) void proj_kernel(
    const float* __restrict__ x,
    const unsigned short* __restrict__ Wh, const float* __restrict__ bfv,
    unsigned short* __restrict__ qH, unsigned short* __restrict__ kH,
    unsigned short* __restrict__ vH)
{
  __shared__ __align__(16) short sm[16384];  // 32 KB
  short* At = sm;          // [128 rows][8 chunks of 8] swizzled
  short* Bt = sm + 8192;   // [128 n][8 chunks] swizzled

  int bid = blockIdx.x;
  int b = bid / 48, rem = bid % 48, mblk = rem >> 3, nblk = rem & 7;
  int Mb = mblk * 128, Nb = nblk * 128;
  int t = threadIdx.x;
  int lane = t & 63, wvid = t >> 6, ln = lane & 15, g = lane >> 4;
  int wm = wvid >> 1, wn = wvid & 1;
  int kgp = t >> 5, lp = t & 31;

  f32x4 acc[4][4];
  for (int i = 0; i < 4; i++)
    for (int j = 0; j < 4; j++) acc[i][j] = (f32x4){0.f, 0.f, 0.f, 0.f};

  for (int kb = 0; kb < 512; kb += 64) {
    __syncthreads();
    // stage A: chunk j stored at position j ^ (row&7)
    for (int ii = 0; ii < 4; ii++) {
      int idx = ii * 256 + t;
      int row = idx >> 3, pos = idx & 7;
      int j = pos ^ (row & 7);
      *(f16x8*)&At[row * 64 + pos * 8] =
          *(const f16x8*)&Wh[(Mb + row) * 512 + kb + j * 8];
    }
    // stage B: k rows kgp*8..+7, n pairs {2lp,2lp+1}+64e, cvt_pkrtz pack
    for (int e = 0; e < 2; e++) {
      float2 f[8];
      for (int rr = 0; rr < 8; rr++)
        f[rr] = *(const float2*)&x[(b * 512 + kb + kgp * 8 + rr) * 1024 +
                                   Nb + 2 * lp + 64 * e];
      int n0 = 2 * lp + 64 * e, n1 = n0 + 1;
      u32x4 h0, h1;
      for (int pr = 0; pr < 4; pr++) {
        h0[pr] = pkh(f[2 * pr].x, f[2 * pr + 1].x);
        h1[pr] = pkh(f[2 * pr].y, f[2 * pr + 1].y);
      }
      *(u32x4*)&Bt[n0 * 64 + 8 * (kgp ^ (n0 & 7))] = h0;
      *(u32x4*)&Bt[n1 * 64 + 8 * (kgp ^ (n1 & 7))] = h1;
    }
    __syncthreads();

    f16x8 af[4][2], bf[4][2];
    for (int mt = 0; mt < 4; mt++)
      for (int ks = 0; ks < 2; ks++) {
        int o = wm * 64 + mt * 16 + ln;
        af[mt][ks] = *(const f16x8*)&At[o * 64 + 8 * ((ks * 4 + g) ^ (o & 7))];
      }
    for (int nt = 0; nt < 4; nt++)
      for (int ks = 0; ks < 2; ks++) {
        int n = wn * 64 + nt * 16 + ln;
        bf[nt][ks] = *(const f16x8*)&Bt[n * 64 + 8 * ((ks * 4 + g) ^ (n & 7))];
      }
    for (int ks = 0; ks < 2; ks++)
      for (int mt = 0; mt < 4; mt++)
        for (int nt = 0; nt < 4; nt++)
          acc[mt][nt] = MFMAH(af[mt][ks], bf[nt][ks], acc[mt][nt]);
  }

  // epilogue: two n-half passes (pass p: waves with wn==p write LDS)
  unsigned* smU = (unsigned*)sm;
  for (int p = 0; p < 2; p++) {
    __syncthreads();
    if (wn == p) {
      if (mblk < 2) {
        // q/k: LDS [nl][o/2] u32 (2 fp16), stride 66 u32, b64 writes
        for (int mt = 0; mt < 4; mt++)
          for (int nt = 0; nt < 4; nt++) {
            float y0 = acc[mt][nt][0] + bfv[Mb + wm * 64 + mt * 16 + g * 4 + 0];
            float y1 = acc[mt][nt][1] + bfv[Mb + wm * 64 + mt * 16 + g * 4 + 1];
            float y2 = acc[mt][nt][2] + bfv[Mb + wm * 64 + mt * 16 + g * 4 + 2];
            float y3 = acc[mt][nt][3] + bfv[Mb + wm * 64 + mt * 16 + g * 4 + 3];
            u32x2 pk = (u32x2){pkh(y0, y1), pkh(y2, y3)};
            int nl = nt * 16 + ln;
            *(u32x2*)&smU[nl * 66 + wm * 32 + mt * 8 + g * 2] = pk;
          }
      } else {
        // v: LDS [o][nl] fp16, stride 72 shorts
        for (int mt = 0; mt < 4; mt++)
          for (int nt = 0; nt < 4; nt++)
            for (int r = 0; r < 4; r++) {
              int o = wm * 64 + mt * 16 + g * 4 + r;
              sm[o * 72 + nt * 16 + ln] = f2h(acc[mt][nt][r] + bfv[Mb + o]);
            }
      }
    }
    __syncthreads();
    if (mblk < 2) {
      unsigned short* dh = (mblk == 0) ? qH : kH;
      for (int it = 0; it < 4; it++) {
        int task = it * 256 + t;
        int h = task >> 8, nl = (task >> 2) & 63, qc = task & 3;
        u32x4 v4 = *(const u32x4*)&smU[nl * 66 + h * 16 + qc * 4];
        int gi = ((b * 4 + h) * 1024 + Nb + p * 64 + nl) * 32 + qc * 8;
        *(u32x4*)&dh[gi] = v4;
      }
    } else {
      int bh = b * 4 + (mblk - 2);
      for (int it = 0; it < 4; it++) {
        int task = it * 256 + t;
        int o = task >> 3, qc = task & 7;
        u32x4 vv = *(const u32x4*)&sm[o * 72 + qc * 8];
        *(u32x4*)&vH[(bh * 128 + o) * 1024 + Nb + p * 64 + qc * 8] = vv;
      }
    }
  }
}

// ---------------------------------------------------------------------------
// Flash attention, fp16, double-buffered gload_lds pipeline.
// LDS per buffer (shorts): K[64][32]@0, Q@2048 (chunk-swizzled:
// pos = ch ^ (r&3) ^ ((r>>2)&3)), V[128][8ch]@4096 (pos = ch ^ (c&7)).
// Buffer = 12288 shorts; dbuf = 48KB. P: per-wave [2 qs][16][72] @24576.
// Schedule: STAGE(next) 6 loads; vmcnt(6); s_barrier; compute(cur); s_barrier.
// Scores S' = log2e*(q.k + pos.q) via pre-scaled q; P = exp2(S'-m').
// ---------------------------------------------------------------------------
__global__ __launch_bounds__(256) void attn_kernel(
    const float* __restrict__ x,
    const unsigned short* __restrict__ qH, const unsigned short* __restrict__ kH,
    const unsigned short* __restrict__ posH, const unsigned short* __restrict__ vH,
    float* __restrict__ out)
{
  __shared__ __align__(16) short sm[24576 + 4 * 2 * 16 * 72];  // 67.5 KB

  int bid = blockIdx.x;
  // XCD-local mapping: all 8 q-tiles of a head on one XCD
  int bh = (bid & 7) * 8 + ((bid >> 3) & 7);
  int qt = bid >> 6;
  int b = bh >> 2, h = bh & 3;
  int t = threadIdx.x;
  int lane = t & 63, wvid = t >> 6, ln = lane & 15, g = lane >> 4;

  // own-query B-fragments (q pre-scaled by log2e; pos unscaled)
  f16x8 bQ[2], bPos[2];
  for (int qs = 0; qs < 2; qs++) {
    int qrow = qt * 128 + wvid * 32 + qs * 16 + ln;
    bQ[qs]   = *(const f16x8*)&qH[(bh * 1024 + qrow) * 32 + g * 8];
    bPos[qs] = *(const f16x8*)&posH[(h * 1024 + qrow) * 32 + g * 8];
  }

  f32x4 acc[2][8];
  for (int qs = 0; qs < 2; qs++)
    for (int ct = 0; ct < 8; ct++) acc[qs][ct] = (f32x4){0.f, 0.f, 0.f, 0.f};
  float m_run[2] = {-1e30f, -1e30f};
  float l_run[2] = {0.f, 0.f};

  short* Pw = &sm[24576 + wvid * 2304];  // per-wave, qs-disjoint halves

  auto STAGE = [&](int bb, int jb) {
    int q = wvid * 64 + lane;
    int r = q >> 2;
    int ch = (q & 3) ^ (r & 3) ^ ((r >> 2) & 3);
    long gq = (long)(bh * 1024 + jb + r) * 32 + ch * 8;
    short* base = &sm[bb * 12288 + wvid * 512];
    gload16(&kH[gq], base);
    gload16(&qH[gq], base + 2048);
    for (int i = 0; i < 4; i++) {
      int qv = (wvid * 4 + i) * 64 + lane;
      int c = qv >> 3;
      int vch = (qv & 7) ^ (c & 7);
      long gv = (long)(bh * 128 + c) * 1024 + jb + vch * 8;
      gload16(&vH[gv], &sm[bb * 12288 + 4096 + (wvid * 4 + i) * 512]);
    }
  };

  STAGE(0, 0);

  for (int it = 0; it < 16; ++it) {
    int cur = it & 1;
    if (it < 15) {
      STAGE(cur ^ 1, (it + 1) * 64);
      asm volatile("s_waitcnt vmcnt(6)" ::: "memory");
    } else {
      asm volatile("s_waitcnt vmcnt(0)" ::: "memory");
    }
    __builtin_amdgcn_s_barrier();
    __builtin_amdgcn_sched_barrier(0);

    const short* B = &sm[cur * 12288];

    f16x8 aK[4], aQ[4];
    for (int kt = 0; kt < 4; kt++) {
      int r = kt * 16 + ln;
      int p = g ^ (r & 3) ^ ((r >> 2) & 3);
      int off = r * 32 + p * 8;
      aK[kt] = *(const f16x8*)&B[off];
      aQ[kt] = *(const f16x8*)&B[2048 + off];
    }

    f16x8 pFrag[2][2];
    for (int qs = 0; qs < 2; qs++) {
      f32x4 s[4];
      for (int kt = 0; kt < 4; kt++) s[kt] = (f32x4){0.f, 0.f, 0.f, 0.f};
      __builtin_amdgcn_s_setprio(1);
      for (int kt = 0; kt < 4; kt++) s[kt] = MFMAH(aK[kt], bQ[qs], s[kt]);
      for (int kt = 0; kt < 4; kt++) s[kt] = MFMAH(aQ[kt], bPos[qs], s[kt]);
      __builtin_amdgcn_s_setprio(0);

      // online softmax in exp2 domain (query i = ln), defer-rescale
      float mx = -1e30f;
      for (int kt = 0; kt < 4; kt++)
        for (int r = 0; r < 4; r++) mx = fmaxf(mx, s[kt][r]);
      mx = fmaxf(mx, __shfl_xor(mx, 16));
      mx = fmaxf(mx, __shfl_xor(mx, 32));
      float mnew;
      if (__any(mx > m_run[qs])) {
        mnew = fmaxf(m_run[qs], mx);
        float scl = __builtin_amdgcn_exp2f(m_run[qs] - mnew);
        l_run[qs] *= scl;
        for (int ct = 0; ct < 8; ct++) acc[qs][ct] *= scl;
      } else {
        mnew = m_run[qs];
      }
      float rs = 0.f;
      for (int kt = 0; kt < 4; kt++)
        for (int r = 0; r < 4; r++) {
          float pv = __builtin_amdgcn_exp2f(s[kt][r] - mnew);
          s[kt][r] = pv;
          rs += pv;
        }
      rs += __shfl_xor(rs, 16);
      rs += __shfl_xor(rs, 32);
      l_run[qs] += rs;
      m_run[qs] = mnew;

      // P^T -> per-wave LDS [i=ln][j] (proven formulas), fp16 pairs
      for (int kt = 0; kt < 4; kt++)
        for (int pr = 0; pr < 2; pr++)
          *(unsigned*)&Pw[qs * 1152 + ln * 72 + kt * 16 + g * 4 + pr * 2] =
              pkh(s[kt][2 * pr], s[kt][2 * pr + 1]);
      asm volatile("s_waitcnt lgkmcnt(0)" ::: "memory");
      __builtin_amdgcn_sched_barrier(0);
      for (int st2 = 0; st2 < 2; st2++)
        pFrag[qs][st2] =
            *(const f16x8*)&Pw[qs * 1152 + ln * 72 + st2 * 32 + g * 8];
    }

    // PV: acc[qs][ct] += V[c][j] * P[i][j]
    __builtin_amdgcn_s_setprio(1);
    for (int ct = 0; ct < 8; ct++)
      for (int st2 = 0; st2 < 2; st2++) {
        int c = ct * 16 + ln;
        int pos = (st2 * 4 + g) ^ (c & 7);
        f16x8 av = *(const f16x8*)&B[4096 + c * 64 + pos * 8];
        acc[0][ct] = MFMAH(av, pFrag[0][st2], acc[0][ct]);
        acc[1][ct] = MFMAH(av, pFrag[1][st2], acc[1][ct]);
      }
    __builtin_amdgcn_s_setprio(0);

    __builtin_amdgcn_s_barrier();
    __builtin_amdgcn_sched_barrier(0);
  }

  // epilogue: normalize, residual, coalesced store (col = m = ln)
  for (int qs = 0; qs < 2; qs++) {
    float inv = 1.0f / l_run[qs];
    int m = qt * 128 + wvid * 32 + qs * 16 + ln;
    for (int ct = 0; ct < 8; ct++)
      for (int r = 0; r < 4; r++) {
        int c = h * 128 + ct * 16 + g * 4 + r;
        int gi = (b * 512 + c) * 1024 + m;
        out[gi] = acc[qs][ct][r] * inv + x[gi];
      }
  }
}

// ---------------------------------------------------------------------------
extern "C" void kernel_launch(void* const* d_in, const int* in_sizes, int n_in,
                              void* d_out, int out_size, void* d_ws, size_t ws_size,
                              hipStream_t stream) {
  const float* x    = (const float*)d_in[0];
  const float* Wq   = (const float*)d_in[1];
  const float* bq   = (const float*)d_in[2];
  const float* qg   = (const float*)d_in[3];
  const float* qbe  = (const float*)d_in[4];
  const float* qme  = (const float*)d_in[5];
  const float* qva  = (const float*)d_in[6];
  const float* Wk   = (const float*)d_in[7];
  const float* bk   = (const float*)d_in[8];
  const float* kg   = (const float*)d_in[9];
  const float* kbe  = (const float*)d_in[10];
  const float* kme  = (const float*)d_in[11];
  const float* kva  = (const float*)d_in[12];
  const float* Wv   = (const float*)d_in[13];
  const float* bv   = (const float*)d_in[14];
  const float* vg   = (const float*)d_in[15];
  const float* vbe  = (const float*)d_in[16];
  const float* vme  = (const float*)d_in[17];
  const float* vva  = (const float*)d_in[18];
  const float* relh = (const float*)d_in[19];
  const float* relw = (const float*)d_in[20];
  float* outp = (float*)d_out;

  unsigned char* ws = (unsigned char*)d_ws;
  unsigned short* Whp  = (unsigned short*)(ws + 0);        // 768*512*2 = 786432
  float*          bfv  = (float*)(ws + 786432);            // 768*4
  unsigned short* qHp  = (unsigned short*)(ws + 789504);   // 64*1024*32*2
  unsigned short* kHp  = (unsigned short*)(ws + 4983808);
  unsigned short* posHp= (unsigned short*)(ws + 9178112);  // 4*1024*32*2
  unsigned short* vHp  = (unsigned short*)(ws + 9440256);  // 64*128*1024*2
  // total ws used: 26,217,472 bytes

  fold_kernel<<<1536, 256, 0, stream>>>(Wq, bq, qg, qbe, qme, qva,
                                        Wk, bk, kg, kbe, kme, kva,
                                        Wv, bv, vg, vbe, vme, vva,
                                        Whp, bfv);
  pos_kernel<<<512, 256, 0, stream>>>(relh, relw, posHp);
  proj_kernel<<<768, 256, 0, stream>>>(x, Whp, bfv, qHp, kHp, vHp);
  attn_kernel<<<512, 256, 0, stream>>>(x, qHp, kHp, posHp, vHp, outp);
}

// Round 7
// 89.151 us; speedup vs baseline: 1.8501x; 1.0862x over previous
//
#include <hip/hip_runtime.h>

// ---------------------------------------------------------------------------
// MHSA fused block, MI355X (gfx950).
// fold(BN->W, fp16, q-rows pre-scaled by log2e) -> pos table (fp16) ->
// QKV projection GEMM (fp16 MFMA single-pass) -> flash attention
// (8-wave/512-thread blocks = 4 waves/SIMD, fp16 scores/P/V, exp2-domain
// softmax with defer-max THR=8, dbuf gload_lds pipeline, XCD-local L2).
// ---------------------------------------------------------------------------

typedef _Float16 f16x8 __attribute__((ext_vector_type(8)));
typedef __attribute__((ext_vector_type(4))) float f32x4;
typedef __attribute__((ext_vector_type(4))) unsigned int u32x4;
typedef __attribute__((ext_vector_type(2))) unsigned int u32x2;

#define MFMAH(a, b, c) __builtin_amdgcn_mfma_f32_16x16x32_f16(a, b, c, 0, 0, 0)
#define LOG2E 1.4426950408889634f

__device__ __forceinline__ unsigned pkh(float a, float b) {
  auto p = __builtin_amdgcn_cvt_pkrtz(a, b);  // __fp16 ext_vector(2)
  return __builtin_bit_cast(unsigned, p);
}
__device__ __forceinline__ short f2h(float a) {
  _Float16 h = (_Float16)a;
  return __builtin_bit_cast(short, h);
}

// 16B global -> LDS direct (wave-uniform LDS base + lane*16)
__device__ __forceinline__ void gload16(const void* g, void* l) {
  __builtin_amdgcn_global_load_lds(
      (const __attribute__((address_space(1))) void*)g,
      (__attribute__((address_space(3))) void*)l, 16, 0, 0);
}

// ---------------------------------------------------------------------------
// Fold BN into conv weights -> fp16. Wh[768][512] (rows: 128 q, 128 k, 512 v).
// q rows (and q bias) pre-scaled by log2e so softmax runs in exp2 domain.
// ---------------------------------------------------------------------------
__global__ __launch_bounds__(256) void fold_kernel(
    const float* __restrict__ Wq, const float* __restrict__ bq,
    const float* __restrict__ qg, const float* __restrict__ qbe,
    const float* __restrict__ qme, const float* __restrict__ qva,
    const float* __restrict__ Wk, const float* __restrict__ bk,
    const float* __restrict__ kg, const float* __restrict__ kbe,
    const float* __restrict__ kme, const float* __restrict__ kva,
    const float* __restrict__ Wv, const float* __restrict__ bv,
    const float* __restrict__ vg, const float* __restrict__ vbe,
    const float* __restrict__ vme, const float* __restrict__ vva,
    unsigned short* __restrict__ Wh, float* __restrict__ bfv)
{
  int idx = blockIdx.x * 256 + threadIdx.x;
  if (idx >= 768 * 512) return;
  int o = idx >> 9, c = idx & 511;
  float w, sc, bb, mean, beta, post;
  if (o < 128) {
    sc = qg[o] / sqrtf(qva[o] + 1e-5f);
    w = Wq[o * 512 + c]; bb = bq[o]; mean = qme[o]; beta = qbe[o];
    post = LOG2E;
  } else if (o < 256) {
    int r = o - 128;
    sc = kg[r] / sqrtf(kva[r] + 1e-5f);
    w = Wk[r * 512 + c]; bb = bk[r]; mean = kme[r]; beta = kbe[r];
    post = 1.0f;
  } else {
    int r = o - 256;
    sc = vg[r] / sqrtf(vva[r] + 1e-5f);
    w = Wv[r * 512 + c]; bb = bv[r]; mean = vme[r]; beta = vbe[r];
    post = 1.0f;
  }
  Wh[idx] = (unsigned short)f2h(w * sc * post);
  if (c == 0) bfv[o] = ((bb - mean) * sc + beta) * post;
}

// ---------------------------------------------------------------------------
// pos[h][n][d] = rel_h[h,d,hh] + rel_w[h,d,w], n = w*32+hh -> fp16.
// (NOT log2e-scaled: the q factor in the cp term carries the scale.)
// ---------------------------------------------------------------------------
__global__ __launch_bounds__(256) void pos_kernel(
    const float* __restrict__ rel_h, const float* __restrict__ rel_w,
    unsigned short* __restrict__ posH)
{
  int idx = blockIdx.x * 256 + threadIdx.x;  // [h][n][d] : 4*1024*32
  if (idx >= 4 * 1024 * 32) return;
  int h = idx >> 15, rem = idx & 32767, n = rem >> 5, d = rem & 31;
  int w = n >> 5, hh = n & 31;
  float v = rel_h[(h * 32 + d) * 32 + hh] + rel_w[(h * 32 + d) * 32 + w];
  posH[idx] = (unsigned short)f2h(v);
}

// ---------------------------------------------------------------------------
// Projection GEMM (unchanged from round 6 — validated).
// ---------------------------------------------------------------------------
__global__ __launch_bounds__(256) void proj_kernel(
    const float* __restrict__ x,
    const unsigned short* __restrict__ Wh, const float* __restrict__ bfv,
    unsigned short* __restrict__ qH, unsigned short* __restrict__ kH,
    unsigned short* __restrict__ vH)
{
  __shared__ __align__(16) short sm[16384];  // 32 KB
  short* At = sm;
  short* Bt = sm + 8192;

  int bid = blockIdx.x;
  int b = bid / 48, rem = bid % 48, mblk = rem >> 3, nblk = rem & 7;
  int Mb = mblk * 128, Nb = nblk * 128;
  int t = threadIdx.x;
  int lane = t & 63, wvid = t >> 6, ln = lane & 15, g = lane >> 4;
  int wm = wvid >> 1, wn = wvid & 1;
  int kgp = t >> 5, lp = t & 31;

  f32x4 acc[4][4];
  for (int i = 0; i < 4; i++)
    for (int j = 0; j < 4; j++) acc[i][j] = (f32x4){0.f, 0.f, 0.f, 0.f};

  for (int kb = 0; kb < 512; kb += 64) {
    __syncthreads();
    for (int ii = 0; ii < 4; ii++) {
      int idx = ii * 256 + t;
      int row = idx >> 3, pos = idx & 7;
      int j = pos ^ (row & 7);
      *(f16x8*)&At[row * 64 + pos * 8] =
          *(const f16x8*)&Wh[(Mb + row) * 512 + kb + j * 8];
    }
    for (int e = 0; e < 2; e++) {
      float2 f[8];
      for (int rr = 0; rr < 8; rr++)
        f[rr] = *(const float2*)&x[(b * 512 + kb + kgp * 8 + rr) * 1024 +
                                   Nb + 2 * lp + 64 * e];
      int n0 = 2 * lp + 64 * e, n1 = n0 + 1;
      u32x4 h0, h1;
      for (int pr = 0; pr < 4; pr++) {
        h0[pr] = pkh(f[2 * pr].x, f[2 * pr + 1].x);
        h1[pr] = pkh(f[2 * pr].y, f[2 * pr + 1].y);
      }
      *(u32x4*)&Bt[n0 * 64 + 8 * (kgp ^ (n0 & 7))] = h0;
      *(u32x4*)&Bt[n1 * 64 + 8 * (kgp ^ (n1 & 7))] = h1;
    }
    __syncthreads();

    f16x8 af[4][2], bf[4][2];
    for (int mt = 0; mt < 4; mt++)
      for (int ks = 0; ks < 2; ks++) {
        int o = wm * 64 + mt * 16 + ln;
        af[mt][ks] = *(const f16x8*)&At[o * 64 + 8 * ((ks * 4 + g) ^ (o & 7))];
      }
    for (int nt = 0; nt < 4; nt++)
      for (int ks = 0; ks < 2; ks++) {
        int n = wn * 64 + nt * 16 + ln;
        bf[nt][ks] = *(const f16x8*)&Bt[n * 64 + 8 * ((ks * 4 + g) ^ (n & 7))];
      }
    for (int ks = 0; ks < 2; ks++)
      for (int mt = 0; mt < 4; mt++)
        for (int nt = 0; nt < 4; nt++)
          acc[mt][nt] = MFMAH(af[mt][ks], bf[nt][ks], acc[mt][nt]);
  }

  unsigned* smU = (unsigned*)sm;
  for (int p = 0; p < 2; p++) {
    __syncthreads();
    if (wn == p) {
      if (mblk < 2) {
        for (int mt = 0; mt < 4; mt++)
          for (int nt = 0; nt < 4; nt++) {
            float y0 = acc[mt][nt][0] + bfv[Mb + wm * 64 + mt * 16 + g * 4 + 0];
            float y1 = acc[mt][nt][1] + bfv[Mb + wm * 64 + mt * 16 + g * 4 + 1];
            float y2 = acc[mt][nt][2] + bfv[Mb + wm * 64 + mt * 16 + g * 4 + 2];
            float y3 = acc[mt][nt][3] + bfv[Mb + wm * 64 + mt * 16 + g * 4 + 3];
            u32x2 pk = (u32x2){pkh(y0, y1), pkh(y2, y3)};
            int nl = nt * 16 + ln;
            *(u32x2*)&smU[nl * 66 + wm * 32 + mt * 8 + g * 2] = pk;
          }
      } else {
        for (int mt = 0; mt < 4; mt++)
          for (int nt = 0; nt < 4; nt++)
            for (int r = 0; r < 4; r++) {
              int o = wm * 64 + mt * 16 + g * 4 + r;
              sm[o * 72 + nt * 16 + ln] = f2h(acc[mt][nt][r] + bfv[Mb + o]);
            }
      }
    }
    __syncthreads();
    if (mblk < 2) {
      unsigned short* dh = (mblk == 0) ? qH : kH;
      for (int it = 0; it < 4; it++) {
        int task = it * 256 + t;
        int h = task >> 8, nl = (task >> 2) & 63, qc = task & 3;
        u32x4 v4 = *(const u32x4*)&smU[nl * 66 + h * 16 + qc * 4];
        int gi = ((b * 4 + h) * 1024 + Nb + p * 64 + nl) * 32 + qc * 8;
        *(u32x4*)&dh[gi] = v4;
      }
    } else {
      int bh = b * 4 + (mblk - 2);
      for (int it = 0; it < 4; it++) {
        int task = it * 256 + t;
        int o = task >> 3, qc = task & 7;
        u32x4 vv = *(const u32x4*)&sm[o * 72 + qc * 8];
        *(u32x4*)&vH[(bh * 128 + o) * 1024 + Nb + p * 64 + qc * 8] = vv;
      }
    }
  }
}

// ---------------------------------------------------------------------------
// Flash attention: 512 threads = 8 waves, each wave owns 16 queries.
// Grid 512 -> 2 blocks/CU -> 16 waves/CU -> 4 waves/SIMD.
// LDS per buffer (shorts): K[64rows][4ch]@0, Qk@2048 (chunk-swizzled:
// pos = ch ^ (r&3) ^ ((r>>2)&3)), V[128c][8ch]@4096 (pos = ch ^ (c&7)).
// Buffer = 12288 shorts; dbuf 48KB; P: per-wave [16][72] @24576 (18KB).
// Staging: 3 gload16/thread (1 K/Q + 2 V); vmcnt(3); s_barrier; compute;
// s_barrier. Softmax: exp2 domain, defer-max THR=8, tree reduce.
// ---------------------------------------------------------------------------
__global__ __launch_bounds__(512, 4) void attn_kernel(
    const float* __restrict__ x,
    const unsigned short* __restrict__ qH, const unsigned short* __restrict__ kH,
    const unsigned short* __restrict__ posH, const unsigned short* __restrict__ vH,
    float* __restrict__ out)
{
  __shared__ __align__(16) short sm[2 * 12288 + 8 * 1152];  // 67584 B

  int bid = blockIdx.x;
  // XCD-local mapping: all 8 q-tiles of a head on one XCD
  int bh = (bid & 7) * 8 + ((bid >> 3) & 7);
  int qt = bid >> 6;
  int b = bh >> 2, h = bh & 3;
  int t = threadIdx.x;
  int lane = t & 63, w = t >> 6, ln = lane & 15, g = (lane >> 4) & 3;

  // own-query fragments (q pre-scaled by log2e; pos unscaled)
  int qrow = qt * 128 + w * 16 + ln;
  f16x8 bQ   = *(const f16x8*)&qH[(bh * 1024 + qrow) * 32 + g * 8];
  f16x8 bPos = *(const f16x8*)&posH[(h * 1024 + qrow) * 32 + g * 8];

  f32x4 acc[8];
  for (int ct = 0; ct < 8; ct++) acc[ct] = (f32x4){0.f, 0.f, 0.f, 0.f};
  float m_run = -1e30f, l_run = 0.f;

  short* Pw = &sm[24576 + w * 1152];

  auto STAGE = [&](int bb, int jb) {
    {  // K (waves 0-3) / Qkey (waves 4-7): 256 units each of 16B
      int u = t & 255;
      int r = u >> 2;
      int ch = (u & 3) ^ (r & 3) ^ ((r >> 2) & 3);
      long gq = (long)(bh * 1024 + jb + r) * 32 + ch * 8;
      const unsigned short* src = (t < 256) ? kH : qH;
      short* base = &sm[bb * 12288 + ((t < 256) ? 0 : 2048) + (w & 3) * 512];
      gload16(&src[gq], base);
    }
    for (int i = 0; i < 2; i++) {  // V: 1024 units of 16B
      int u = t + i * 512;
      int c = u >> 3;
      int vch = (u & 7) ^ (c & 7);
      long gv = (long)(bh * 128 + c) * 1024 + jb + vch * 8;
      short* base = &sm[bb * 12288 + 4096 + (w + i * 8) * 512];
      gload16(&vH[gv], base);
    }
  };

  STAGE(0, 0);

  for (int it = 0; it < 16; ++it) {
    int cur = it & 1;
    if (it < 15) {
      STAGE(cur ^ 1, (it + 1) * 64);
      asm volatile("s_waitcnt vmcnt(3)" ::: "memory");
    } else {
      asm volatile("s_waitcnt vmcnt(0)" ::: "memory");
    }
    __builtin_amdgcn_s_barrier();
    __builtin_amdgcn_sched_barrier(0);

    const short* B = &sm[cur * 12288];

    f16x8 aK[4], aQ[4];
    for (int kt = 0; kt < 4; kt++) {
      int r = kt * 16 + ln;
      int p = g ^ (r & 3) ^ ((r >> 2) & 3);
      int off = r * 32 + p * 8;
      aK[kt] = *(const f16x8*)&B[off];
      aQ[kt] = *(const f16x8*)&B[2048 + off];
    }

    f32x4 s[4];
    for (int kt = 0; kt < 4; kt++) s[kt] = (f32x4){0.f, 0.f, 0.f, 0.f};
    __builtin_amdgcn_s_setprio(1);
    for (int kt = 0; kt < 4; kt++) s[kt] = MFMAH(aK[kt], bQ, s[kt]);
    for (int kt = 0; kt < 4; kt++) s[kt] = MFMAH(aQ[kt], bPos, s[kt]);
    __builtin_amdgcn_s_setprio(0);

    // online softmax, exp2 domain, defer-max THR=8, tree reductions
    float m0 = fmaxf(fmaxf(s[0][0], s[0][1]), fmaxf(s[0][2], s[0][3]));
    float m1 = fmaxf(fmaxf(s[1][0], s[1][1]), fmaxf(s[1][2], s[1][3]));
    float m2 = fmaxf(fmaxf(s[2][0], s[2][1]), fmaxf(s[2][2], s[2][3]));
    float m3 = fmaxf(fmaxf(s[3][0], s[3][1]), fmaxf(s[3][2], s[3][3]));
    float mx = fmaxf(fmaxf(m0, m1), fmaxf(m2, m3));
    mx = fmaxf(mx, __shfl_xor(mx, 16));
    mx = fmaxf(mx, __shfl_xor(mx, 32));
    if (__any(mx > m_run + 8.f)) {
      float mnew = fmaxf(m_run, mx);
      float scl = __builtin_amdgcn_exp2f(m_run - mnew);
      l_run *= scl;
      for (int ct = 0; ct < 8; ct++) acc[ct] *= scl;
      m_run = mnew;
    }
    for (int kt = 0; kt < 4; kt++)
      for (int r = 0; r < 4; r++)
        s[kt][r] = __builtin_amdgcn_exp2f(s[kt][r] - m_run);
    float r0 = (s[0][0] + s[0][1]) + (s[0][2] + s[0][3]);
    float r1 = (s[1][0] + s[1][1]) + (s[1][2] + s[1][3]);
    float r2 = (s[2][0] + s[2][1]) + (s[2][2] + s[2][3]);
    float r3 = (s[3][0] + s[3][1]) + (s[3][2] + s[3][3]);
    float rs = (r0 + r1) + (r2 + r3);
    rs += __shfl_xor(rs, 16);
    rs += __shfl_xor(rs, 32);
    l_run += rs;

    // P^T -> per-wave LDS [i=ln][j] (proven formulas), 4 x b64
    for (int kt = 0; kt < 4; kt++) {
      u32x2 pk = (u32x2){pkh(s[kt][0], s[kt][1]), pkh(s[kt][2], s[kt][3])};
      *(u32x2*)&Pw[ln * 72 + kt * 16 + g * 4] = pk;
    }
    asm volatile("s_waitcnt lgkmcnt(0)" ::: "memory");
    __builtin_amdgcn_sched_barrier(0);
    f16x8 pFrag[2];
    for (int st2 = 0; st2 < 2; st2++)
      pFrag[st2] = *(const f16x8*)&Pw[ln * 72 + st2 * 32 + g * 8];

    // PV: acc[ct] += V[c][j] * P[i][j]
    __builtin_amdgcn_s_setprio(1);
    for (int ct = 0; ct < 8; ct++)
      for (int st2 = 0; st2 < 2; st2++) {
        int c = ct * 16 + ln;
        int pos = (st2 * 4 + g) ^ (c & 7);
        f16x8 av = *(const f16x8*)&B[4096 + c * 64 + pos * 8];
        acc[ct] = MFMAH(av, pFrag[st2], acc[ct]);
      }
    __builtin_amdgcn_s_setprio(0);

    __builtin_amdgcn_sched_barrier(0);
    __builtin_amdgcn_s_barrier();
    __builtin_amdgcn_sched_barrier(0);
  }

  // epilogue: normalize, residual, store (col = m = ln)
  float inv = 1.0f / l_run;
  int m = qt * 128 + w * 16 + ln;
  for (int ct = 0; ct < 8; ct++)
    for (int r = 0; r < 4; r++) {
      int c = h * 128 + ct * 16 + g * 4 + r;
      int gi = (b * 512 + c) * 1024 + m;
      out[gi] = acc[ct][r] * inv + x[gi];
    }
}

// ---------------------------------------------------------------------------
extern "C" void kernel_launch(void* const* d_in, const int* in_sizes, int n_in,
                              void* d_out, int out_size, void* d_ws, size_t ws_size,
                              hipStream_t stream) {
  const float* x    = (const float*)d_in[0];
  const float* Wq   = (const float*)d_in[1];
  const float* bq   = (const float*)d_in[2];
  const float* qg   = (const float*)d_in[3];
  const float* qbe  = (const float*)d_in[4];
  const float* qme  = (const float*)d_in[5];
  const float* qva  = (const float*)d_in[6];
  const float* Wk   = (const float*)d_in[7];
  const float* bk   = (const float*)d_in[8];
  const float* kg   = (const float*)d_in[9];
  const float* kbe  = (const float*)d_in[10];
  const float* kme  = (const float*)d_in[11];
  const float* kva  = (const float*)d_in[12];
  const float* Wv   = (const float*)d_in[13];
  const float* bv   = (const float*)d_in[14];
  const float* vg   = (const float*)d_in[15];
  const float* vbe  = (const float*)d_in[16];
  const float* vme  = (const float*)d_in[17];
  const float* vva  = (const float*)d_in[18];
  const float* relh = (const float*)d_in[19];
  const float* relw = (const float*)d_in[20];
  float* outp = (float*)d_out;

  unsigned char* ws = (unsigned char*)d_ws;
  unsigned short* Whp  = (unsigned short*)(ws + 0);        // 768*512*2
  float*          bfv  = (float*)(ws + 786432);            // 768*4
  unsigned short* qHp  = (unsigned short*)(ws + 789504);   // 64*1024*32*2
  unsigned short* kHp  = (unsigned short*)(ws + 4983808);
  unsigned short* posHp= (unsigned short*)(ws + 9178112);  // 4*1024*32*2
  unsigned short* vHp  = (unsigned short*)(ws + 9440256);  // 64*128*1024*2
  // total ws used: 26,217,472 bytes

  fold_kernel<<<1536, 256, 0, stream>>>(Wq, bq, qg, qbe, qme, qva,
                                        Wk, bk, kg, kbe, kme, kva,
                                        Wv, bv, vg, vbe, vme, vva,
                                        Whp, bfv);
  pos_kernel<<<512, 256, 0, stream>>>(relh, relw, posHp);
  proj_kernel<<<768, 256, 0, stream>>>(x, Whp, bfv, qHp, kHp, vHp);
  attn_kernel<<<512, 512, 0, stream>>>(x, qHp, kHp, posHp, vHp, outp);
}

// Round 8
// 87.592 us; speedup vs baseline: 1.8830x; 1.0178x over previous
//
#include <hip/hip_runtime.h>

// ---------------------------------------------------------------------------
// MHSA fused block, MI355X (gfx950).
// fold(BN->W, fp16, q-rows pre-scaled by log2e) -> pos table (fp16) ->
// QKV projection GEMM (fp16 MFMA single-pass) -> flash attention
// (8-wave/512-thread blocks, fp16 scores/P/V, exp2-domain softmax with
// local-max fast path, l-sum via ones-channel MFMA, dbuf gload_lds
// pipeline, XCD-local L2 reuse).
// ---------------------------------------------------------------------------

typedef _Float16 f16x8 __attribute__((ext_vector_type(8)));
typedef __attribute__((ext_vector_type(4))) float f32x4;
typedef __attribute__((ext_vector_type(4))) unsigned int u32x4;
typedef __attribute__((ext_vector_type(2))) unsigned int u32x2;

#define MFMAH(a, b, c) __builtin_amdgcn_mfma_f32_16x16x32_f16(a, b, c, 0, 0, 0)
#define LOG2E 1.4426950408889634f

__device__ __forceinline__ unsigned pkh(float a, float b) {
  auto p = __builtin_amdgcn_cvt_pkrtz(a, b);  // __fp16 ext_vector(2)
  return __builtin_bit_cast(unsigned, p);
}
__device__ __forceinline__ short f2h(float a) {
  _Float16 h = (_Float16)a;
  return __builtin_bit_cast(short, h);
}

// 16B global -> LDS direct (wave-uniform LDS base + lane*16)
__device__ __forceinline__ void gload16(const void* g, void* l) {
  __builtin_amdgcn_global_load_lds(
      (const __attribute__((address_space(1))) void*)g,
      (__attribute__((address_space(3))) void*)l, 16, 0, 0);
}

// ---------------------------------------------------------------------------
// Fold BN into conv weights -> fp16. Wh[768][512] (rows: 128 q, 128 k, 512 v).
// q rows (and q bias) pre-scaled by log2e so softmax runs in exp2 domain.
// ---------------------------------------------------------------------------
__global__ __launch_bounds__(256) void fold_kernel(
    const float* __restrict__ Wq, const float* __restrict__ bq,
    const float* __restrict__ qg, const float* __restrict__ qbe,
    const float* __restrict__ qme, const float* __restrict__ qva,
    const float* __restrict__ Wk, const float* __restrict__ bk,
    const float* __restrict__ kg, const float* __restrict__ kbe,
    const float* __restrict__ kme, const float* __restrict__ kva,
    const float* __restrict__ Wv, const float* __restrict__ bv,
    const float* __restrict__ vg, const float* __restrict__ vbe,
    const float* __restrict__ vme, const float* __restrict__ vva,
    unsigned short* __restrict__ Wh, float* __restrict__ bfv)
{
  int idx = blockIdx.x * 256 + threadIdx.x;
  if (idx >= 768 * 512) return;
  int o = idx >> 9, c = idx & 511;
  float w, sc, bb, mean, beta, post;
  if (o < 128) {
    sc = qg[o] / sqrtf(qva[o] + 1e-5f);
    w = Wq[o * 512 + c]; bb = bq[o]; mean = qme[o]; beta = qbe[o];
    post = LOG2E;
  } else if (o < 256) {
    int r = o - 128;
    sc = kg[r] / sqrtf(kva[r] + 1e-5f);
    w = Wk[r * 512 + c]; bb = bk[r]; mean = kme[r]; beta = kbe[r];
    post = 1.0f;
  } else {
    int r = o - 256;
    sc = vg[r] / sqrtf(vva[r] + 1e-5f);
    w = Wv[r * 512 + c]; bb = bv[r]; mean = vme[r]; beta = vbe[r];
    post = 1.0f;
  }
  Wh[idx] = (unsigned short)f2h(w * sc * post);
  if (c == 0) bfv[o] = ((bb - mean) * sc + beta) * post;
}

// ---------------------------------------------------------------------------
// pos[h][n][d] = rel_h[h,d,hh] + rel_w[h,d,w], n = w*32+hh -> fp16.
// (NOT log2e-scaled: the q factor in the cp term carries the scale.)
// ---------------------------------------------------------------------------
__global__ __launch_bounds__(256) void pos_kernel(
    const float* __restrict__ rel_h, const float* __restrict__ rel_w,
    unsigned short* __restrict__ posH)
{
  int idx = blockIdx.x * 256 + threadIdx.x;  // [h][n][d] : 4*1024*32
  if (idx >= 4 * 1024 * 32) return;
  int h = idx >> 15, rem = idx & 32767, n = rem >> 5, d = rem & 31;
  int w = n >> 5, hh = n & 31;
  float v = rel_h[(h * 32 + d) * 32 + hh] + rel_w[(h * 32 + d) * 32 + w];
  posH[idx] = (unsigned short)f2h(v);
}

// ---------------------------------------------------------------------------
// Projection GEMM (unchanged from round 6/7 — validated).
// ---------------------------------------------------------------------------
__global__ __launch_bounds__(256) void proj_kernel(
    const float* __restrict__ x,
    const unsigned short* __restrict__ Wh, const float* __restrict__ bfv,
    unsigned short* __restrict__ qH, unsigned short* __restrict__ kH,
    unsigned short* __restrict__ vH)
{
  __shared__ __align__(16) short sm[16384];  // 32 KB
  short* At = sm;
  short* Bt = sm + 8192;

  int bid = blockIdx.x;
  int b = bid / 48, rem = bid % 48, mblk = rem >> 3, nblk = rem & 7;
  int Mb = mblk * 128, Nb = nblk * 128;
  int t = threadIdx.x;
  int lane = t & 63, wvid = t >> 6, ln = lane & 15, g = lane >> 4;
  int wm = wvid >> 1, wn = wvid & 1;
  int kgp = t >> 5, lp = t & 31;

  f32x4 acc[4][4];
  for (int i = 0; i < 4; i++)
    for (int j = 0; j < 4; j++) acc[i][j] = (f32x4){0.f, 0.f, 0.f, 0.f};

  for (int kb = 0; kb < 512; kb += 64) {
    __syncthreads();
    for (int ii = 0; ii < 4; ii++) {
      int idx = ii * 256 + t;
      int row = idx >> 3, pos = idx & 7;
      int j = pos ^ (row & 7);
      *(f16x8*)&At[row * 64 + pos * 8] =
          *(const f16x8*)&Wh[(Mb + row) * 512 + kb + j * 8];
    }
    for (int e = 0; e < 2; e++) {
      float2 f[8];
      for (int rr = 0; rr < 8; rr++)
        f[rr] = *(const float2*)&x[(b * 512 + kb + kgp * 8 + rr) * 1024 +
                                   Nb + 2 * lp + 64 * e];
      int n0 = 2 * lp + 64 * e, n1 = n0 + 1;
      u32x4 h0, h1;
      for (int pr = 0; pr < 4; pr++) {
        h0[pr] = pkh(f[2 * pr].x, f[2 * pr + 1].x);
        h1[pr] = pkh(f[2 * pr].y, f[2 * pr + 1].y);
      }
      *(u32x4*)&Bt[n0 * 64 + 8 * (kgp ^ (n0 & 7))] = h0;
      *(u32x4*)&Bt[n1 * 64 + 8 * (kgp ^ (n1 & 7))] = h1;
    }
    __syncthreads();

    f16x8 af[4][2], bf[4][2];
    for (int mt = 0; mt < 4; mt++)
      for (int ks = 0; ks < 2; ks++) {
        int o = wm * 64 + mt * 16 + ln;
        af[mt][ks] = *(const f16x8*)&At[o * 64 + 8 * ((ks * 4 + g) ^ (o & 7))];
      }
    for (int nt = 0; nt < 4; nt++)
      for (int ks = 0; ks < 2; ks++) {
        int n = wn * 64 + nt * 16 + ln;
        bf[nt][ks] = *(const f16x8*)&Bt[n * 64 + 8 * ((ks * 4 + g) ^ (n & 7))];
      }
    for (int ks = 0; ks < 2; ks++)
      for (int mt = 0; mt < 4; mt++)
        for (int nt = 0; nt < 4; nt++)
          acc[mt][nt] = MFMAH(af[mt][ks], bf[nt][ks], acc[mt][nt]);
  }

  unsigned* smU = (unsigned*)sm;
  for (int p = 0; p < 2; p++) {
    __syncthreads();
    if (wn == p) {
      if (mblk < 2) {
        for (int mt = 0; mt < 4; mt++)
          for (int nt = 0; nt < 4; nt++) {
            float y0 = acc[mt][nt][0] + bfv[Mb + wm * 64 + mt * 16 + g * 4 + 0];
            float y1 = acc[mt][nt][1] + bfv[Mb + wm * 64 + mt * 16 + g * 4 + 1];
            float y2 = acc[mt][nt][2] + bfv[Mb + wm * 64 + mt * 16 + g * 4 + 2];
            float y3 = acc[mt][nt][3] + bfv[Mb + wm * 64 + mt * 16 + g * 4 + 3];
            u32x2 pk = (u32x2){pkh(y0, y1), pkh(y2, y3)};
            int nl = nt * 16 + ln;
            *(u32x2*)&smU[nl * 66 + wm * 32 + mt * 8 + g * 2] = pk;
          }
      } else {
        for (int mt = 0; mt < 4; mt++)
          for (int nt = 0; nt < 4; nt++)
            for (int r = 0; r < 4; r++) {
              int o = wm * 64 + mt * 16 + g * 4 + r;
              sm[o * 72 + nt * 16 + ln] = f2h(acc[mt][nt][r] + bfv[Mb + o]);
            }
      }
    }
    __syncthreads();
    if (mblk < 2) {
      unsigned short* dh = (mblk == 0) ? qH : kH;
      for (int it = 0; it < 4; it++) {
        int task = it * 256 + t;
        int h = task >> 8, nl = (task >> 2) & 63, qc = task & 3;
        u32x4 v4 = *(const u32x4*)&smU[nl * 66 + h * 16 + qc * 4];
        int gi = ((b * 4 + h) * 1024 + Nb + p * 64 + nl) * 32 + qc * 8;
        *(u32x4*)&dh[gi] = v4;
      }
    } else {
      int bh = b * 4 + (mblk - 2);
      for (int it = 0; it < 4; it++) {
        int task = it * 256 + t;
        int o = task >> 3, qc = task & 7;
        u32x4 vv = *(const u32x4*)&sm[o * 72 + qc * 8];
        *(u32x4*)&vH[(bh * 128 + o) * 1024 + Nb + p * 64 + qc * 8] = vv;
      }
    }
  }
}

// ---------------------------------------------------------------------------
// Flash attention: 512 threads = 8 waves, each wave owns 16 queries.
// Grid 512 -> 2 blocks/CU -> 4 waves/SIMD.
// LDS per buffer (shorts): K[64rows][4ch]@0, Qk@2048 (chunk-swizzled:
// pos = ch ^ (r&3) ^ ((r>>2)&3)), V[128c][8ch]@4096 (pos = ch ^ (c&7)).
// Buffer = 12288 shorts; dbuf 48KB; P: per-wave [16][72] @24576 (18KB).
// Softmax: exp2 domain; lane-local max fast path (cross-lane max+rescale
// only when local max > m_run+8); row-sum l via ones-channel MFMA into
// acc[8] (rescales with acc; recovered by one shfl in epilogue).
// ---------------------------------------------------------------------------
__global__ __launch_bounds__(512, 4) void attn_kernel(
    const float* __restrict__ x,
    const unsigned short* __restrict__ qH, const unsigned short* __restrict__ kH,
    const unsigned short* __restrict__ posH, const unsigned short* __restrict__ vH,
    float* __restrict__ out)
{
  __shared__ __align__(16) short sm[2 * 12288 + 8 * 1152];  // 67584 B

  int bid = blockIdx.x;
  // XCD-local mapping: all 8 q-tiles of a head on one XCD
  int bh = (bid & 7) * 8 + ((bid >> 3) & 7);
  int qt = bid >> 6;
  int b = bh >> 2, h = bh & 3;
  int t = threadIdx.x;
  int lane = t & 63, w = t >> 6, ln = lane & 15, g = (lane >> 4) & 3;

  // own-query fragments (q pre-scaled by log2e; pos unscaled)
  int qrow = qt * 128 + w * 16 + ln;
  f16x8 bQ   = *(const f16x8*)&qH[(bh * 1024 + qrow) * 32 + g * 8];
  f16x8 bPos = *(const f16x8*)&posH[(h * 1024 + qrow) * 32 + g * 8];

  // ones-channel A-fragment: A[m][k] = (m==0) ? 1 : 0; lane ln holds row m=ln
  f16x8 aOnes;
  {
    _Float16 o1 = (ln == 0) ? (_Float16)1.0f : (_Float16)0.0f;
    for (int i = 0; i < 8; i++) aOnes[i] = o1;
  }

  f32x4 acc[9];  // [0..7] = output channels, [8] = l row-sum (m=0 row)
  for (int ct = 0; ct < 9; ct++) acc[ct] = (f32x4){0.f, 0.f, 0.f, 0.f};
  float m_run = -1e30f;

  short* Pw = &sm[24576 + w * 1152];

  auto STAGE = [&](int bb, int jb) {
    {  // K (waves 0-3) / Qkey (waves 4-7): 256 units each of 16B
      int u = t & 255;
      int r = u >> 2;
      int ch = (u & 3) ^ (r & 3) ^ ((r >> 2) & 3);
      long gq = (long)(bh * 1024 + jb + r) * 32 + ch * 8;
      const unsigned short* src = (t < 256) ? kH : qH;
      short* base = &sm[bb * 12288 + ((t < 256) ? 0 : 2048) + (w & 3) * 512];
      gload16(&src[gq], base);
    }
    for (int i = 0; i < 2; i++) {  // V: 1024 units of 16B
      int u = t + i * 512;
      int c = u >> 3;
      int vch = (u & 7) ^ (c & 7);
      long gv = (long)(bh * 128 + c) * 1024 + jb + vch * 8;
      short* base = &sm[bb * 12288 + 4096 + (w + i * 8) * 512];
      gload16(&vH[gv], base);
    }
  };

  STAGE(0, 0);

  for (int it = 0; it < 16; ++it) {
    int cur = it & 1;
    if (it < 15) {
      STAGE(cur ^ 1, (it + 1) * 64);
      asm volatile("s_waitcnt vmcnt(3)" ::: "memory");
    } else {
      asm volatile("s_waitcnt vmcnt(0)" ::: "memory");
    }
    __builtin_amdgcn_s_barrier();
    __builtin_amdgcn_sched_barrier(0);

    const short* B = &sm[cur * 12288];

    f16x8 aK[4], aQ[4];
    for (int kt = 0; kt < 4; kt++) {
      int r = kt * 16 + ln;
      int p = g ^ (r & 3) ^ ((r >> 2) & 3);
      int off = r * 32 + p * 8;
      aK[kt] = *(const f16x8*)&B[off];
      aQ[kt] = *(const f16x8*)&B[2048 + off];
    }

    f32x4 s[4];
    for (int kt = 0; kt < 4; kt++) s[kt] = (f32x4){0.f, 0.f, 0.f, 0.f};
    __builtin_amdgcn_s_setprio(1);
    for (int kt = 0; kt < 4; kt++) s[kt] = MFMAH(aK[kt], bQ, s[kt]);
    for (int kt = 0; kt < 4; kt++) s[kt] = MFMAH(aQ[kt], bPos, s[kt]);
    __builtin_amdgcn_s_setprio(0);

    // lane-local max (no cross-lane in common path)
    float m0 = fmaxf(fmaxf(s[0][0], s[0][1]), fmaxf(s[0][2], s[0][3]));
    float m1 = fmaxf(fmaxf(s[1][0], s[1][1]), fmaxf(s[1][2], s[1][3]));
    float m2 = fmaxf(fmaxf(s[2][0], s[2][1]), fmaxf(s[2][2], s[2][3]));
    float m3 = fmaxf(fmaxf(s[3][0], s[3][1]), fmaxf(s[3][2], s[3][3]));
    float mx = fmaxf(fmaxf(m0, m1), fmaxf(m2, m3));
    if (__any(mx > m_run + 8.f)) {  // rare: cross-lane max + rescale
      float mxf = fmaxf(mx, __shfl_xor(mx, 16));
      mxf = fmaxf(mxf, __shfl_xor(mxf, 32));
      float mnew = fmaxf(m_run, mxf);
      float scl = __builtin_amdgcn_exp2f(m_run - mnew);
      for (int ct = 0; ct < 9; ct++) acc[ct] *= scl;
      m_run = mnew;
    }
    for (int kt = 0; kt < 4; kt++)
      for (int r = 0; r < 4; r++)
        s[kt][r] = __builtin_amdgcn_exp2f(s[kt][r] - m_run);

    // P^T -> per-wave LDS [i=ln][j] (proven formulas), 4 x b64
    for (int kt = 0; kt < 4; kt++) {
      u32x2 pk = (u32x2){pkh(s[kt][0], s[kt][1]), pkh(s[kt][2], s[kt][3])};
      *(u32x2*)&Pw[ln * 72 + kt * 16 + g * 4] = pk;
    }
    asm volatile("s_waitcnt lgkmcnt(0)" ::: "memory");
    __builtin_amdgcn_sched_barrier(0);
    f16x8 pFrag[2];
    for (int st2 = 0; st2 < 2; st2++)
      pFrag[st2] = *(const f16x8*)&Pw[ln * 72 + st2 * 32 + g * 8];

    // PV: acc[ct] += V[c][j] * P[i][j]; acc[8] += 1(m=0) * P = row-sum l
    __builtin_amdgcn_s_setprio(1);
    for (int ct = 0; ct < 8; ct++)
      for (int st2 = 0; st2 < 2; st2++) {
        int c = ct * 16 + ln;
        int pos = (st2 * 4 + g) ^ (c & 7);
        f16x8 av = *(const f16x8*)&B[4096 + c * 64 + pos * 8];
        acc[ct] = MFMAH(av, pFrag[st2], acc[ct]);
      }
    acc[8] = MFMAH(aOnes, pFrag[0], acc[8]);
    acc[8] = MFMAH(aOnes, pFrag[1], acc[8]);
    __builtin_amdgcn_s_setprio(0);

    __builtin_amdgcn_sched_barrier(0);
    __builtin_amdgcn_s_barrier();
    __builtin_amdgcn_sched_barrier(0);
  }

  // epilogue: l lives in (g=0, r=0) lane of each query; broadcast, normalize
  float lsum = __shfl(acc[8][0], ln);  // lane ln = (ln, g=0)
  float inv = 1.0f / lsum;
  int m = qt * 128 + w * 16 + ln;
  for (int ct = 0; ct < 8; ct++)
    for (int r = 0; r < 4; r++) {
      int c = h * 128 + ct * 16 + g * 4 + r;
      int gi = (b * 512 + c) * 1024 + m;
      out[gi] = acc[ct][r] * inv + x[gi];
    }
}

// ---------------------------------------------------------------------------
extern "C" void kernel_launch(void* const* d_in, const int* in_sizes, int n_in,
                              void* d_out, int out_size, void* d_ws, size_t ws_size,
                              hipStream_t stream) {
  const float* x    = (const float*)d_in[0];
  const float* Wq   = (const float*)d_in[1];
  const float* bq   = (const float*)d_in[2];
  const float* qg   = (const float*)d_in[3];
  const float* qbe  = (const float*)d_in[4];
  const float* qme  = (const float*)d_in[5];
  const float* qva  = (const float*)d_in[6];
  const float* Wk   = (const float*)d_in[7];
  const float* bk   = (const float*)d_in[8];
  const float* kg   = (const float*)d_in[9];
  const float* kbe  = (const float*)d_in[10];
  const float* kme  = (const float*)d_in[11];
  const float* kva  = (const float*)d_in[12];
  const float* Wv   = (const float*)d_in[13];
  const float* bv   = (const float*)d_in[14];
  const float* vg   = (const float*)d_in[15];
  const float* vbe  = (const float*)d_in[16];
  const float* vme  = (const float*)d_in[17];
  const float* vva  = (const float*)d_in[18];
  const float* relh = (const float*)d_in[19];
  const float* relw = (const float*)d_in[20];
  float* outp = (float*)d_out;

  unsigned char* ws = (unsigned char*)d_ws;
  unsigned short* Whp  = (unsigned short*)(ws + 0);        // 768*512*2
  float*          bfv  = (float*)(ws + 786432);            // 768*4
  unsigned short* qHp  = (unsigned short*)(ws + 789504);   // 64*1024*32*2
  unsigned short* kHp  = (unsigned short*)(ws + 4983808);
  unsigned short* posHp= (unsigned short*)(ws + 9178112);  // 4*1024*32*2
  unsigned short* vHp  = (unsigned short*)(ws + 9440256);  // 64*128*1024*2
  // total ws used: 26,217,472 bytes

  fold_kernel<<<1536, 256, 0, stream>>>(Wq, bq, qg, qbe, qme, qva,
                                        Wk, bk, kg, kbe, kme, kva,
                                        Wv, bv, vg, vbe, vme, vva,
                                        Whp, bfv);
  pos_kernel<<<512, 256, 0, stream>>>(relh, relw, posHp);
  proj_kernel<<<768, 256, 0, stream>>>(x, Whp, bfv, qHp, kHp, vHp);
  attn_kernel<<<512, 512, 0, stream>>>(x, qHp, kHp, posHp, vHp, outp);
}